// Round 4
// baseline (1362.423 us; speedup 1.0000x reference)
//
#include <hip/hip_runtime.h>
#include <math.h>

#define NN 131072
#define EE 2097152
#define ET (EE + NN)
#define GG 512
#define BN_EPS 1e-5f

// ---------------- CSR build ----------------
__global__ void k_hist(const int* __restrict__ ei, int* __restrict__ cnt) {
  int e = blockIdx.x * blockDim.x + threadIdx.x;
  if (e < EE) atomicAdd(&cnt[ei[EE + e]], 1);
}

__global__ void k_scan_a(const int* __restrict__ cnt, int* __restrict__ off_out,
                         int* __restrict__ bsum) {
  __shared__ int s[256];
  int i = blockIdx.x * 256 + threadIdx.x;
  int x = cnt[i] + 1;  // +1 self loop
  s[threadIdx.x] = x;
  __syncthreads();
#pragma unroll
  for (int o = 1; o < 256; o <<= 1) {
    int t = (threadIdx.x >= o) ? s[threadIdx.x - o] : 0;
    __syncthreads();
    s[threadIdx.x] += t;
    __syncthreads();
  }
  off_out[i] = s[threadIdx.x] - x;  // exclusive within block
  if (threadIdx.x == 255) bsum[blockIdx.x] = s[255];
}

__global__ void k_scan_b(int* __restrict__ bsum) {
  __shared__ int s[512];
  int t = threadIdx.x;
  int x = bsum[t];
  s[t] = x;
  __syncthreads();
#pragma unroll
  for (int o = 1; o < 512; o <<= 1) {
    int v = (t >= o) ? s[t - o] : 0;
    __syncthreads();
    s[t] += v;
    __syncthreads();
  }
  bsum[t] = s[t] - x;  // exclusive, in place
}

__global__ void k_scan_c(int* __restrict__ off_out, const int* __restrict__ bsum) {
  int i = blockIdx.x * 256 + threadIdx.x;
  off_out[i] += bsum[blockIdx.x];
  if (i == 0) off_out[NN] = ET;
}

__global__ void k_scatter(const int* __restrict__ ei, const float* __restrict__ ea,
                          const int* __restrict__ off, int* __restrict__ cur,
                          int* __restrict__ csrc, float4* __restrict__ cea) {
  int e = blockIdx.x * blockDim.x + threadIdx.x;
  if (e >= EE) return;
  int s = ei[e], d = ei[EE + e];
  int p = off[d] + atomicAdd(&cur[d], 1);
  csrc[p] = s;
  float4 t = {ea[3 * e], ea[3 * e + 1], ea[3 * e + 2], 0.0f};
  cea[p] = t;
}

// self-loop slot = last slot of each node; attr = mean of incoming real-edge attrs
__global__ void k_selfloop(const int* __restrict__ off, int* __restrict__ csrc,
                           float4* __restrict__ cea) {
  int v = blockIdx.x * blockDim.x + threadIdx.x;
  if (v >= NN) return;
  int b = off[v];
  int d = off[v + 1] - b - 1;  // real in-degree
  float s0 = 0.f, s1 = 0.f, s2 = 0.f;
  for (int j = b; j < b + d; j++) {
    float4 t = cea[j];
    s0 += t.x;
    s1 += t.y;
    s2 += t.z;
  }
  float inv = 1.0f / (float)(d > 0 ? d : 1);
  int sl = b + d;
  csrc[sl] = v;
  float4 t = {s0 * inv, s1 * inv, s2 * inv, 0.0f};
  cea[sl] = t;
}

// ---------------- node linear: xl = f(x)@wl+bl ; xr = f(x)@wr+br ----------------
template <int K, int O, bool DO_BN>
__global__ void k_lin(const float* __restrict__ x, const float* __restrict__ wl,
                      const float* __restrict__ bl, const float* __restrict__ wr,
                      const float* __restrict__ br, float* __restrict__ xl,
                      float* __restrict__ xr, const float* __restrict__ bnsum,
                      const float* __restrict__ bnss, const float* __restrict__ g,
                      const float* __restrict__ be) {
  constexpr int NPB = 256 / O;  // nodes per block-iteration
  __shared__ float swl[K * O], swr[K * O], sx[NPB * K];
  __shared__ float sscale[K], sshift[K];
  for (int i = threadIdx.x; i < K * O; i += 256) {
    swl[i] = wl[i];
    swr[i] = wr[i];
  }
  if (DO_BN && threadIdx.x < K) {
    int c = threadIdx.x;
    float mu = bnsum[c] * (1.0f / NN);
    float var = bnss[c] * (1.0f / NN) - mu * mu;
    float is = rsqrtf(var + BN_EPS) * g[c];
    sscale[c] = is;
    sshift[c] = be[c] - mu * is;
  }
  int o = threadIdx.x % O;
  int ln = threadIdx.x / O;
  float blv = bl[o], brv = br[o];
  __syncthreads();
  for (int v0 = blockIdx.x * NPB; v0 < NN; v0 += gridDim.x * NPB) {
    __syncthreads();
    for (int i = threadIdx.x; i < NPB * K; i += 256) {
      float xv = x[(size_t)v0 * K + i];
      if (DO_BN) {
        int c = i & (K - 1);
        xv = xv * sscale[c] + sshift[c];
        xv = (xv > 0.0f) ? xv : (__expf(xv) - 1.0f);
      }
      sx[i] = xv;
    }
    __syncthreads();
    float al = blv, ar = brv;
#pragma unroll 8
    for (int k = 0; k < K; k++) {
      float xv = sx[ln * K + k];
      al += xv * swl[k * O + o];
      ar += xv * swr[k * O + o];
    }
    int v = v0 + ln;
    xl[(size_t)v * O + o] = al;
    xr[(size_t)v * O + o] = ar;
  }
}

// ---------------- fused GATv2 edge phase ----------------
// One wave per node, full-wave coalesced rows (head = lane>>5). 4 edges per
// iteration, 2-stage software pipeline: indices for group g+2 and rows/attrs
// for group g+1 are in flight while computing group g (~12 outstanding VMEM).
// No running max (logits bounded; exp in fp32 safe — validated R3).

__device__ __forceinline__ void half_reduce4(float& a, float& b, float& c, float& d) {
#pragma unroll
  for (int m = 16; m >= 1; m >>= 1) {  // masks <32 keep the two halves separate
    a += __shfl_xor(a, m, 64);
    b += __shfl_xor(b, m, 64);
    c += __shfl_xor(c, m, 64);
    d += __shfl_xor(d, m, 64);
  }
}

// HC=128: float2/lane (lane holds channels 2*lane, 2*lane+1; head = lane>>5)
__global__ void k_gat128(const int* __restrict__ off, const int* __restrict__ csrc,
                         const float4* __restrict__ cea, const float2* __restrict__ xl,
                         const float2* __restrict__ xr, const float2* __restrict__ we,
                         const float2* __restrict__ att, const float2* __restrict__ bias,
                         float2* __restrict__ hout, float* __restrict__ bnsum,
                         float* __restrict__ bnss) {
  __shared__ float lsum[4][64], lsq[4][64];
  int lane = threadIdx.x & 63;
  int wid = threadIdx.x >> 6;
  const float2 w0 = we[lane], w1 = we[64 + lane], w2 = we[128 + lane];
  const float2 av = att[lane];
  float2 rs = {0, 0}, rq = {0, 0};
  for (int v = blockIdx.x * 4 + wid; v < NN; v += gridDim.x * 4) {
    int b = off[v], e = off[v + 1];
    int last = e - 1;
    float2 xrv = xr[(size_t)v * 64 + lane];
    float ssum = 0.0f;
    float2 acc = {0, 0};
    // prologue: group0 idx/ea/rows, group1 idx
    int i0 = csrc[b], i1 = csrc[min(b + 1, last)], i2 = csrc[min(b + 2, last)],
        i3 = csrc[min(b + 3, last)];
    float4 ea0 = cea[b], ea1 = cea[min(b + 1, last)], ea2 = cea[min(b + 2, last)],
           ea3 = cea[min(b + 3, last)];
    float2 r0 = xl[(size_t)i0 * 64 + lane], r1 = xl[(size_t)i1 * 64 + lane],
           r2 = xl[(size_t)i2 * 64 + lane], r3 = xl[(size_t)i3 * 64 + lane];
    int n0 = csrc[min(b + 4, last)], n1 = csrc[min(b + 5, last)],
        n2 = csrc[min(b + 6, last)], n3 = csrc[min(b + 7, last)];
    for (int j = b; j < e; j += 4) {
      // prefetch: attrs+rows for group j+4, indices for group j+8
      float4 na0 = cea[min(j + 4, last)], na1 = cea[min(j + 5, last)],
             na2 = cea[min(j + 6, last)], na3 = cea[min(j + 7, last)];
      float2 nr0 = xl[(size_t)n0 * 64 + lane], nr1 = xl[(size_t)n1 * 64 + lane],
             nr2 = xl[(size_t)n2 * 64 + lane], nr3 = xl[(size_t)n3 * 64 + lane];
      int m0 = csrc[min(j + 8, last)], m1 = csrc[min(j + 9, last)],
          m2 = csrc[min(j + 10, last)], m3 = csrc[min(j + 11, last)];
      // compute 4 edges (independent chains)
      float ax, ay, l0, l1, l2, l3;
      ax = r0.x + xrv.x + ea0.x * w0.x + ea0.y * w1.x + ea0.z * w2.x;
      ay = r0.y + xrv.y + ea0.x * w0.y + ea0.y * w1.y + ea0.z * w2.y;
      ax = fmaxf(ax, 0.2f * ax); ay = fmaxf(ay, 0.2f * ay);
      l0 = ax * av.x + ay * av.y;
      ax = r1.x + xrv.x + ea1.x * w0.x + ea1.y * w1.x + ea1.z * w2.x;
      ay = r1.y + xrv.y + ea1.x * w0.y + ea1.y * w1.y + ea1.z * w2.y;
      ax = fmaxf(ax, 0.2f * ax); ay = fmaxf(ay, 0.2f * ay);
      l1 = ax * av.x + ay * av.y;
      ax = r2.x + xrv.x + ea2.x * w0.x + ea2.y * w1.x + ea2.z * w2.x;
      ay = r2.y + xrv.y + ea2.x * w0.y + ea2.y * w1.y + ea2.z * w2.y;
      ax = fmaxf(ax, 0.2f * ax); ay = fmaxf(ay, 0.2f * ay);
      l2 = ax * av.x + ay * av.y;
      ax = r3.x + xrv.x + ea3.x * w0.x + ea3.y * w1.x + ea3.z * w2.x;
      ay = r3.y + xrv.y + ea3.x * w0.y + ea3.y * w1.y + ea3.z * w2.y;
      ax = fmaxf(ax, 0.2f * ax); ay = fmaxf(ay, 0.2f * ay);
      l3 = ax * av.x + ay * av.y;
      half_reduce4(l0, l1, l2, l3);
      float p0 = __expf(l0);
      float p1 = (j + 1 < e) ? __expf(l1) : 0.0f;
      float p2 = (j + 2 < e) ? __expf(l2) : 0.0f;
      float p3 = (j + 3 < e) ? __expf(l3) : 0.0f;
      ssum += (p0 + p1) + (p2 + p3);
      acc.x += p0 * r0.x + p1 * r1.x + p2 * r2.x + p3 * r3.x;
      acc.y += p0 * r0.y + p1 * r1.y + p2 * r2.y + p3 * r3.y;
      // rotate pipeline
      ea0 = na0; ea1 = na1; ea2 = na2; ea3 = na3;
      r0 = nr0; r1 = nr1; r2 = nr2; r3 = nr3;
      n0 = m0; n1 = m1; n2 = m2; n3 = m3;
    }
    float inv = 1.0f / (ssum + 1e-16f);
    float2 o = {acc.x * inv, acc.y * inv};
    float px = __shfl_xor(o.x, 32, 64);
    float py = __shfl_xor(o.y, 32, 64);
    if (lane < 32) {
      float2 bv = bias[lane];
      float2 val = {0.5f * (o.x + px) + bv.x, 0.5f * (o.y + py) + bv.y};
      hout[(size_t)v * 32 + lane] = val;
      rs.x += val.x; rs.y += val.y;
      rq.x += val.x * val.x; rq.y += val.y * val.y;
    }
  }
  if (lane < 32) {
    lsum[wid][2 * lane] = rs.x;
    lsum[wid][2 * lane + 1] = rs.y;
    lsq[wid][2 * lane] = rq.x;
    lsq[wid][2 * lane + 1] = rq.y;
  }
  __syncthreads();
  if (threadIdx.x < 64) {
    float a = lsum[0][threadIdx.x] + lsum[1][threadIdx.x] + lsum[2][threadIdx.x] +
              lsum[3][threadIdx.x];
    float q = lsq[0][threadIdx.x] + lsq[1][threadIdx.x] + lsq[2][threadIdx.x] +
              lsq[3][threadIdx.x];
    atomicAdd(&bnsum[threadIdx.x], a);
    atomicAdd(&bnss[threadIdx.x], q);
  }
}

// HC=64: float/lane (lane = channel; head = lane>>5)
__global__ void k_gat64(const int* __restrict__ off, const int* __restrict__ csrc,
                        const float4* __restrict__ cea, const float* __restrict__ xl,
                        const float* __restrict__ xr, const float* __restrict__ we,
                        const float* __restrict__ att, const float* __restrict__ bias,
                        float* __restrict__ hout, float* __restrict__ bnsum,
                        float* __restrict__ bnss) {
  __shared__ float lsum[4][32], lsq[4][32];
  int lane = threadIdx.x & 63;
  int wid = threadIdx.x >> 6;
  const float w0 = we[lane], w1 = we[64 + lane], w2 = we[128 + lane];
  const float av = att[lane];
  float rs = 0.0f, rq = 0.0f;
  for (int v = blockIdx.x * 4 + wid; v < NN; v += gridDim.x * 4) {
    int b = off[v], e = off[v + 1];
    int last = e - 1;
    float xrv = xr[(size_t)v * 64 + lane];
    float ssum = 0.0f, acc = 0.0f;
    int i0 = csrc[b], i1 = csrc[min(b + 1, last)], i2 = csrc[min(b + 2, last)],
        i3 = csrc[min(b + 3, last)];
    float4 ea0 = cea[b], ea1 = cea[min(b + 1, last)], ea2 = cea[min(b + 2, last)],
           ea3 = cea[min(b + 3, last)];
    float r0 = xl[(size_t)i0 * 64 + lane], r1 = xl[(size_t)i1 * 64 + lane],
          r2 = xl[(size_t)i2 * 64 + lane], r3 = xl[(size_t)i3 * 64 + lane];
    int n0 = csrc[min(b + 4, last)], n1 = csrc[min(b + 5, last)],
        n2 = csrc[min(b + 6, last)], n3 = csrc[min(b + 7, last)];
    for (int j = b; j < e; j += 4) {
      float4 na0 = cea[min(j + 4, last)], na1 = cea[min(j + 5, last)],
             na2 = cea[min(j + 6, last)], na3 = cea[min(j + 7, last)];
      float nr0 = xl[(size_t)n0 * 64 + lane], nr1 = xl[(size_t)n1 * 64 + lane],
            nr2 = xl[(size_t)n2 * 64 + lane], nr3 = xl[(size_t)n3 * 64 + lane];
      int m0 = csrc[min(j + 8, last)], m1 = csrc[min(j + 9, last)],
          m2 = csrc[min(j + 10, last)], m3 = csrc[min(j + 11, last)];
      float t, l0, l1, l2, l3;
      t = r0 + xrv + ea0.x * w0 + ea0.y * w1 + ea0.z * w2;
      t = fmaxf(t, 0.2f * t); l0 = t * av;
      t = r1 + xrv + ea1.x * w0 + ea1.y * w1 + ea1.z * w2;
      t = fmaxf(t, 0.2f * t); l1 = t * av;
      t = r2 + xrv + ea2.x * w0 + ea2.y * w1 + ea2.z * w2;
      t = fmaxf(t, 0.2f * t); l2 = t * av;
      t = r3 + xrv + ea3.x * w0 + ea3.y * w1 + ea3.z * w2;
      t = fmaxf(t, 0.2f * t); l3 = t * av;
      half_reduce4(l0, l1, l2, l3);
      float p0 = __expf(l0);
      float p1 = (j + 1 < e) ? __expf(l1) : 0.0f;
      float p2 = (j + 2 < e) ? __expf(l2) : 0.0f;
      float p3 = (j + 3 < e) ? __expf(l3) : 0.0f;
      ssum += (p0 + p1) + (p2 + p3);
      acc += p0 * r0 + p1 * r1 + p2 * r2 + p3 * r3;
      ea0 = na0; ea1 = na1; ea2 = na2; ea3 = na3;
      r0 = nr0; r1 = nr1; r2 = nr2; r3 = nr3;
      n0 = m0; n1 = m1; n2 = m2; n3 = m3;
    }
    float o = acc / (ssum + 1e-16f);
    float po = __shfl_xor(o, 32, 64);
    if (lane < 32) {
      float val = 0.5f * (o + po) + bias[lane];
      hout[(size_t)v * 32 + lane] = val;
      rs += val;
      rq += val * val;
    }
  }
  if (lane < 32) {
    lsum[wid][lane] = rs;
    lsq[wid][lane] = rq;
  }
  __syncthreads();
  if (threadIdx.x < 32) {
    float a = lsum[0][threadIdx.x] + lsum[1][threadIdx.x] + lsum[2][threadIdx.x] +
              lsum[3][threadIdx.x];
    float q = lsq[0][threadIdx.x] + lsq[1][threadIdx.x] + lsq[2][threadIdx.x] +
              lsq[3][threadIdx.x];
    atomicAdd(&bnsum[threadIdx.x], a);
    atomicAdd(&bnss[threadIdx.x], q);
  }
}

// ---------------- pooling (fused BN2+ELU) + head ----------------
__global__ void k_gcount(const int* __restrict__ batch, int* __restrict__ gcount) {
  int v = blockIdx.x * blockDim.x + threadIdx.x;
  if (v < NN) atomicAdd(&gcount[batch[v]], 1);
}

__global__ void k_goff(const int* __restrict__ gcount, int* __restrict__ goff) {
  __shared__ int s[GG];
  int t = threadIdx.x;
  int x = gcount[t];
  s[t] = x;
  __syncthreads();
#pragma unroll
  for (int o = 1; o < GG; o <<= 1) {
    int v = (t >= o) ? s[t - o] : 0;
    __syncthreads();
    s[t] += v;
    __syncthreads();
  }
  goff[t] = s[t] - x;
}

__global__ void k_pool(const float* __restrict__ h2, const int* __restrict__ goff,
                       const int* __restrict__ gcount, const float* __restrict__ bnsum,
                       const float* __restrict__ bnss, const float* __restrict__ g,
                       const float* __restrict__ be, float* __restrict__ pooled) {
  int gi = blockIdx.x, c = threadIdx.x;  // 64 threads
  float mu = bnsum[c] * (1.0f / NN);
  float var = bnss[c] * (1.0f / NN) - mu * mu;
  float is = rsqrtf(var + BN_EPS) * g[c];
  float sh = be[c] - mu * is;
  int s = goff[gi], n = gcount[gi];
  float acc = 0.0f;
  for (int i = 0; i < n; i++) {
    float y = h2[(size_t)(s + i) * 64 + c] * is + sh;
    y = (y > 0.0f) ? y : (__expf(y) - 1.0f);
    acc += y;
  }
  pooled[gi * 64 + c] = acc / fmaxf((float)n, 1.0f);
}

__global__ void k_fc1(const float* __restrict__ pooled, const float* __restrict__ w,
                      const float* __restrict__ b, float* __restrict__ t1) {
  int i = blockIdx.x * blockDim.x + threadIdx.x;  // 16384
  int g = i >> 5, o = i & 31;
  float acc = b[o];
#pragma unroll 8
  for (int k = 0; k < 64; k++) acc += pooled[g * 64 + k] * w[k * 32 + o];
  t1[i] = acc;
}

__global__ void k_head(const float* __restrict__ t1, const float* __restrict__ g3,
                       const float* __restrict__ be3, const float* __restrict__ fc2w,
                       const float* __restrict__ fc2b, float* __restrict__ out) {
  __shared__ float ssum[32], ssq[32], smu[32], sinv[32];
  int t = threadIdx.x;  // 512 threads, one per graph
  if (t < 32) {
    ssum[t] = 0.0f;
    ssq[t] = 0.0f;
  }
  __syncthreads();
  float y[32];
#pragma unroll
  for (int o = 0; o < 32; o++) y[o] = t1[t * 32 + o];
#pragma unroll
  for (int o = 0; o < 32; o++) {
    atomicAdd(&ssum[o], y[o]);
    atomicAdd(&ssq[o], y[o] * y[o]);
  }
  __syncthreads();
  if (t < 32) {
    float mu = ssum[t] * (1.0f / GG);
    float var = ssq[t] * (1.0f / GG) - mu * mu;
    smu[t] = mu;
    sinv[t] = rsqrtf(var + BN_EPS);
  }
  __syncthreads();
  float acc = fc2b[0];
#pragma unroll
  for (int o = 0; o < 32; o++) {
    float yy = (y[o] - smu[o]) * sinv[o] * g3[o] + be3[o];
    yy = (yy > 0.0f) ? yy : (__expf(yy) - 1.0f);
    acc += yy * fc2w[o];
  }
  out[t] = 1.0f / (1.0f + __expf(-acc));
}

// ---------------- launch ----------------
extern "C" void kernel_launch(void* const* d_in, const int* in_sizes, int n_in,
                              void* d_out, int out_size, void* d_ws, size_t ws_size,
                              hipStream_t stream) {
  const float* x = (const float*)d_in[0];
  const float* ea = (const float*)d_in[1];
  const float* w1l = (const float*)d_in[2];
  const float* b1l = (const float*)d_in[3];
  const float* w1r = (const float*)d_in[4];
  const float* b1r = (const float*)d_in[5];
  const float* w1e = (const float*)d_in[6];
  const float* att1 = (const float*)d_in[7];
  const float* bias1 = (const float*)d_in[8];
  const float* g1 = (const float*)d_in[9];
  const float* be1 = (const float*)d_in[10];
  const float* w2l = (const float*)d_in[11];
  const float* b2l = (const float*)d_in[12];
  const float* w2r = (const float*)d_in[13];
  const float* b2r = (const float*)d_in[14];
  const float* w2e = (const float*)d_in[15];
  const float* att2 = (const float*)d_in[16];
  const float* bias2 = (const float*)d_in[17];
  const float* g2 = (const float*)d_in[18];
  const float* be2 = (const float*)d_in[19];
  const float* fc1w = (const float*)d_in[20];
  const float* fc1b = (const float*)d_in[21];
  const float* g3 = (const float*)d_in[22];
  const float* be3 = (const float*)d_in[23];
  const float* fc2w = (const float*)d_in[24];
  const float* fc2b = (const float*)d_in[25];
  const int* ei = (const int*)d_in[26];
  const int* batch = (const int*)d_in[27];
  float* out = (float*)d_out;

  char* w = (char*)d_ws;
  size_t off = 0;
  auto alloc = [&](size_t bytes) {
    size_t r = off;
    off += (bytes + 255) & ~(size_t)255;
    return r;
  };
  // zero-init region (one memset)
  int* cnt = (int*)(w + alloc(NN * 4));
  int* cur = (int*)(w + alloc(NN * 4));
  int* gcount = (int*)(w + alloc(GG * 4));
  float* bn1sum = (float*)(w + alloc(32 * 4));
  float* bn1ss = (float*)(w + alloc(32 * 4));
  float* bn2sum = (float*)(w + alloc(64 * 4));
  float* bn2ss = (float*)(w + alloc(64 * 4));
  size_t zero_bytes = off;
  // rest
  int* csr_off = (int*)(w + alloc((size_t)(NN + 1) * 4));
  int* bsum = (int*)(w + alloc(512 * 4));
  int* goff = (int*)(w + alloc((size_t)(GG + 1) * 4));
  int* csrc = (int*)(w + alloc((size_t)ET * 4));
  float4* cea = (float4*)(w + alloc((size_t)ET * 16));
  float* xl = (float*)(w + alloc((size_t)NN * 128 * 4));
  float* xr = (float*)(w + alloc((size_t)NN * 128 * 4));
  float* h1 = (float*)(w + alloc((size_t)NN * 32 * 4));
  float* h2 = (float*)(w + alloc((size_t)NN * 64 * 4));
  float* pooled = (float*)(w + alloc((size_t)GG * 64 * 4));
  float* t1 = (float*)(w + alloc((size_t)GG * 32 * 4));
  (void)ws_size;
  (void)in_sizes;
  (void)n_in;
  (void)out_size;

  hipMemsetAsync(d_ws, 0, zero_bytes, stream);

  // CSR build
  k_hist<<<EE / 256, 256, 0, stream>>>(ei, cnt);
  k_scan_a<<<512, 256, 0, stream>>>(cnt, csr_off, bsum);
  k_scan_b<<<1, 512, 0, stream>>>(bsum);
  k_scan_c<<<512, 256, 0, stream>>>(csr_off, bsum);
  k_scatter<<<EE / 256, 256, 0, stream>>>(ei, ea, csr_off, cur, csrc, cea);
  k_selfloop<<<NN / 256, 256, 0, stream>>>(csr_off, csrc, cea);

  // layer 1 (HC=64, C=32)
  k_lin<64, 64, false><<<2048, 256, 0, stream>>>(x, w1l, b1l, w1r, b1r, xl, xr,
                                                 nullptr, nullptr, nullptr, nullptr);
  k_gat64<<<2048, 256, 0, stream>>>(csr_off, csrc, cea, xl, xr, w1e, att1, bias1,
                                    h1, bn1sum, bn1ss);

  // layer 2 (HC=128, C=64) — BN1+ELU fused into the staging load
  k_lin<32, 128, true><<<2048, 256, 0, stream>>>(h1, w2l, b2l, w2r, b2r, xl, xr,
                                                 bn1sum, bn1ss, g1, be1);
  k_gat128<<<2048, 256, 0, stream>>>(csr_off, csrc, cea, (const float2*)xl,
                                     (const float2*)xr, (const float2*)w2e,
                                     (const float2*)att2, (const float2*)bias2,
                                     (float2*)h2, bn2sum, bn2ss);

  // pooling (BN2+ELU fused) + head
  k_gcount<<<NN / 256, 256, 0, stream>>>(batch, gcount);
  k_goff<<<1, GG, 0, stream>>>(gcount, goff);
  k_pool<<<GG, 64, 0, stream>>>(h2, goff, gcount, bn2sum, bn2ss, g2, be2, pooled);
  k_fc1<<<64, 256, 0, stream>>>(pooled, fc1w, fc1b, t1);
  k_head<<<1, GG, 0, stream>>>(t1, g3, be3, fc2w, fc2b, out);
}